// Round 7
// baseline (2432.248 us; speedup 1.0000x reference)
//
#include <hip/hip_runtime.h>

#define V 16000
#define E 256
#define H 512
#define HP 516     // padded LDS row stride
#define BB 8       // batch = greedy rows
#define T 12       // lenseq
#define NB 256     // persistent blocks
#define TPB 512    // threads per block
#define AGENT __HIP_MEMORY_SCOPE_AGENT

// Greedy degeneracy verified (R3). Persistent kernel since R4.
// R6 lesson: per-step time == (17MB HBM miss)/371GB/s -> phase B is
// latency-bound on w_out (L2 thrash at 4.05MB/XCD vs 4MB L2) with ~0.5
// outstanding misses/wave. R7: double-buffered batched register prefetch
// (16 float4 in flight/thread) to pipeline HBM misses at BW, plus a
// low-traffic barrier (leaf counters -> block0 aggregator -> 1 epoch word).

__device__ __forceinline__ float dot4(float4 a, float4 b) {
    return a.x * b.x + a.y * b.y + a.z * b.z + a.w * b.w;
}

__global__ __launch_bounds__(256) void kinit(const float* __restrict__ hidden,
                                             float* __restrict__ hA,
                                             int* __restrict__ leaf,
                                             int* __restrict__ epoch) {
    int idx = blockIdx.x * 256 + threadIdx.x;
    if (idx < BB * H) hA[idx] = hidden[idx];
    if (idx < 64 * 16) leaf[idx] = 0;
    if (idx == 0) epoch[0] = 0;
}

// stage h (written via agent atomics) into padded LDS
__device__ __forceinline__ void stage_h(const float* __restrict__ g,
                                        float* __restrict__ s_h, int tid) {
    int r  = tid >> 6;          // 0..7
    int k0 = (tid & 63) * 8;    // 8 floats per thread
    const unsigned long long* p = (const unsigned long long*)(g + r * H + k0);
    float* d = s_h + r * HP + k0;
#pragma unroll
    for (int i = 0; i < 4; i++) {
        unsigned long long q = __hip_atomic_load(p + i, __ATOMIC_RELAXED, AGENT);
        union { unsigned long long u; float f[2]; } cv; cv.u = q;
        d[2 * i] = cv.f[0]; d[2 * i + 1] = cv.f[1];
    }
}

// barrier: leaf arrival (4 blocks/leaf, padded) -> block0 wave0 watches the 64
// leaves -> publishes epoch -> everyone else polls ONE word with ONE lane.
__device__ __forceinline__ void gridbar(int* __restrict__ leaf,
                                        int* __restrict__ epoch, int ep) {
    __syncthreads();
    if (threadIdx.x == 0) {
        int g = blockIdx.x >> 2;
        __hip_atomic_fetch_add(&leaf[g * 16], 1, __ATOMIC_RELEASE, AGENT);
    }
    if (blockIdx.x == 0) {
        if (threadIdx.x < 64) {
            while (__hip_atomic_load(&leaf[threadIdx.x * 16],
                                     __ATOMIC_RELAXED, AGENT) < 4 * ep)
                __builtin_amdgcn_s_sleep(1);
        }
        __syncthreads();
        if (threadIdx.x == 0)
            __hip_atomic_store(epoch, ep, __ATOMIC_RELAXED, AGENT);
    } else {
        if (threadIdx.x == 0) {
            while (__hip_atomic_load(epoch, __ATOMIC_RELAXED, AGENT) < ep)
                __builtin_amdgcn_s_sleep(1);
        }
    }
    __builtin_amdgcn_fence(__ATOMIC_ACQUIRE, "workgroup");
    __syncthreads();
}

__global__ __launch_bounds__(TPB) void kmain(
    const float* __restrict__ emb_tab,
    const float* __restrict__ w_ih,
    const float* __restrict__ w_hh,
    const float* __restrict__ b_ih,
    const float* __restrict__ b_hh,
    const float* __restrict__ w_out,
    const float* __restrict__ b_out,
    float* __restrict__ hA,
    float* __restrict__ hB,
    float* __restrict__ psum,   // [2][8][NB]
    float* __restrict__ pval,
    int* __restrict__ pidx,
    int* __restrict__ leaf,
    int* __restrict__ epoch,
    float* __restrict__ out)
{
    const int blk = blockIdx.x, tid = threadIdx.x;

    __shared__ float s_h[BB * HP];          // 16.5 KB
    __shared__ float s_part[64 * 48];       // 12 KB (phase A only)
    __shared__ float s_v[TPB];
    __shared__ float s_av[TPB];
    __shared__ int   s_ai[TPB];
    __shared__ float s_S[BB];
    __shared__ int   s_Xn[BB];
    __shared__ int   s_X[BB];

    if (tid < BB) s_X[tid] = 1;             // SOS
    __syncthreads();

    const int r  = tid & 7;
    const int vl = tid >> 3;                // 0..63
    const int v  = blk * 64 + vl;
    const bool ok = (v < V);
    float e = 0.f;                          // exp(logit), persists B -> C

    for (int t = 0; t < T; t++) {
        const float* h_cur = (t & 1) ? hB : hA;
        float*       h_nxt = (t & 1) ? hA : hB;
        const int par = t & 1;

        // ---------------- phase A: GRU cell (blocks 0..63) ----------------
        if (blk < 64) {
            stage_h(h_cur, s_h, tid);
            __syncthreads();
            const int jl = tid >> 6;        // 0..7
            const int ar = (tid >> 3) & 7;  // row
            const int kq = tid & 7;         // K split 8
            const int j  = blk * 8 + jl;
            const int pair = jl * 8 + ar;
            float gir = 0.f, giz = 0.f, gin = 0.f, ghr = 0.f, ghz = 0.f, ghn = 0.f;
            {
                const float* erow = emb_tab + (size_t)s_X[ar] * E;
                const float* w0 = w_ih + (size_t)j * E;
                const float* w1 = w0 + (size_t)H * E;
                const float* w2 = w1 + (size_t)H * E;
                const int k0 = kq * (E / 8);
#pragma unroll
                for (int k = 0; k < E / 8; k += 4) {
                    float4 ev = *(const float4*)(erow + k0 + k);
                    gir += dot4(*(const float4*)(w0 + k0 + k), ev);
                    giz += dot4(*(const float4*)(w1 + k0 + k), ev);
                    gin += dot4(*(const float4*)(w2 + k0 + k), ev);
                }
            }
            {
                const float* hrow = s_h + ar * HP;
                const float* w0 = w_hh + (size_t)j * H;
                const float* w1 = w0 + (size_t)H * H;
                const float* w2 = w1 + (size_t)H * H;
                const int k0 = kq * (H / 8);
#pragma unroll
                for (int k = 0; k < H / 8; k += 4) {
                    float4 hv = *(const float4*)(hrow + k0 + k);
                    ghr += dot4(*(const float4*)(w0 + k0 + k), hv);
                    ghz += dot4(*(const float4*)(w1 + k0 + k), hv);
                    ghn += dot4(*(const float4*)(w2 + k0 + k), hv);
                }
            }
            float* sp = s_part + pair * 48;
            sp[0 * 8 + kq] = gir; sp[1 * 8 + kq] = giz; sp[2 * 8 + kq] = gin;
            sp[3 * 8 + kq] = ghr; sp[4 * 8 + kq] = ghz; sp[5 * 8 + kq] = ghn;
            __syncthreads();
            if (kq == 0) {
                const float* sp2 = s_part + pair * 48;
                float G[6];
#pragma unroll
                for (int gg = 0; gg < 6; gg++) {
                    float s = 0.f;
#pragma unroll
                    for (int q = 0; q < 8; q++) s += sp2[gg * 8 + q];
                    G[gg] = s;
                }
                float ir  = G[0] + b_ih[j],         hr_ = G[3] + b_hh[j];
                float iz  = G[1] + b_ih[H + j],     hz  = G[4] + b_hh[H + j];
                float inn = G[2] + b_ih[2 * H + j], hn  = G[5] + b_hh[2 * H + j];
                float rg = 1.f / (1.f + __expf(-(ir + hr_)));
                float zg = 1.f / (1.f + __expf(-(iz + hz)));
                float ng = tanhf(inn + rg * hn);
                float ho = s_h[ar * HP + j];
                int xr = s_X[ar];
                bool dn = (xr == 0) || (xr == 2);
                float hv = dn ? ho : ((1.f - zg) * ng + zg * ho);
                __hip_atomic_store(&h_nxt[ar * H + j], hv, __ATOMIC_RELAXED, AGENT);
            }
        }
        gridbar(leaf, epoch, 2 * t + 1);

        // -------- phase B: logits with double-buffered register prefetch ---
        stage_h(h_nxt, s_h, tid);
        __syncthreads();
        {
            const float* w  = w_out + (size_t)(ok ? v : 0) * H;
            const float* hr = s_h + r * HP;
            float4 A0[8], A1[8];
            float a0 = 0.f, a1 = 0.f, a2 = 0.f, a3 = 0.f;
#pragma unroll
            for (int i = 0; i < 8; i++) A0[i] = *(const float4*)(w + 4 * i);
#pragma unroll
            for (int c = 0; c < 16; c += 2) {
#pragma unroll
                for (int i = 0; i < 8; i++)            // prefetch chunk c+1
                    A1[i] = *(const float4*)(w + (c + 1) * 32 + 4 * i);
#pragma unroll
                for (int i = 0; i < 8; i++) {          // consume chunk c
                    float4 h4 = *(const float4*)(hr + c * 32 + 4 * i);
                    float d = dot4(A0[i], h4);
                    if (i == 0 || i == 4) a0 += d;
                    else if (i == 1 || i == 5) a1 += d;
                    else if (i == 2 || i == 6) a2 += d;
                    else a3 += d;
                }
                if (c + 2 < 16) {
#pragma unroll
                    for (int i = 0; i < 8; i++)        // prefetch chunk c+2
                        A0[i] = *(const float4*)(w + (c + 2) * 32 + 4 * i);
                }
#pragma unroll
                for (int i = 0; i < 8; i++) {          // consume chunk c+1
                    float4 h4 = *(const float4*)(hr + (c + 1) * 32 + 4 * i);
                    float d = dot4(A1[i], h4);
                    if (i == 0 || i == 4) a0 += d;
                    else if (i == 1 || i == 5) a1 += d;
                    else if (i == 2 || i == 6) a2 += d;
                    else a3 += d;
                }
            }
            e = __expf((a0 + a1) + (a2 + a3) + (ok ? b_out[v] : 0.f));
            s_v[tid]  = ok ? e : 0.f;
            s_av[tid] = ok ? e : -1.f;
            s_ai[tid] = ok ? v : 0x7fffffff;
        }
        __syncthreads();
        for (int s = 256; s >= 8; s >>= 1) {
            if (tid < s) {
                s_v[tid] += s_v[tid + s];
                float ov = s_av[tid + s]; int oi = s_ai[tid + s];
                if (ov > s_av[tid] || (ov == s_av[tid] && oi < s_ai[tid])) {
                    s_av[tid] = ov; s_ai[tid] = oi;
                }
            }
            __syncthreads();
        }
        if (tid < 8) {
            int o = (par * 8 + tid) * NB + blk;    // [par][row][blk]
            __hip_atomic_store(&psum[o], s_v[tid],  __ATOMIC_RELAXED, AGENT);
            __hip_atomic_store(&pval[o], s_av[tid], __ATOMIC_RELAXED, AGENT);
            __hip_atomic_store(&pidx[o], s_ai[tid], __ATOMIC_RELAXED, AGENT);
        }
        gridbar(leaf, epoch, 2 * t + 2);

        // ------- phase C: redundant global reduce + out write + x update ---
        {
            const int rw = tid >> 6;            // wave -> row
            const int lane = tid & 63;
            const int base = (par * 8 + rw) * NB;
            float s = 0.f, bv = -1.f; int bi = 0x7fffffff;
#pragma unroll
            for (int c = 0; c < 4; c++) {       // coalesced: lane-contiguous
                int o = base + lane + 64 * c;
                s += __hip_atomic_load(&psum[o], __ATOMIC_RELAXED, AGENT);
                float ov = __hip_atomic_load(&pval[o], __ATOMIC_RELAXED, AGENT);
                int   oi = __hip_atomic_load(&pidx[o], __ATOMIC_RELAXED, AGENT);
                if (ov > bv || (ov == bv && oi < bi)) { bv = ov; bi = oi; }
            }
            for (int m = 1; m < 64; m <<= 1) {
                s += __shfl_xor(s, m, 64);
                float ov = __shfl_xor(bv, m, 64);
                int   oi = __shfl_xor(bi, m, 64);
                if (ov > bv || (ov == bv && oi < bi)) { bv = ov; bi = oi; }
            }
            if (lane == 0) { s_S[rw] = s; s_Xn[rw] = bi; }
        }
        __syncthreads();
        {
            float* out_t = out + (size_t)t * BB * V;
            int xr = s_X[r];
            bool dn = (xr == 0) || (xr == 2);
            float inv = 1.f / s_S[r];
            if (ok) {
                float val = dn ? ((v == 0) ? 1.f : 0.f) : e * inv;
                __builtin_nontemporal_store(val, out_t + r * V + v);
            }
        }
        __syncthreads();
        if (tid < 8) {
            int xo = s_X[tid];
            s_X[tid] = ((xo == 0) || (xo == 2)) ? 0 : s_Xn[tid];
        }
        __syncthreads();
    }
}

extern "C" void kernel_launch(void* const* d_in, const int* in_sizes, int n_in,
                              void* d_out, int out_size, void* d_ws, size_t ws_size,
                              hipStream_t stream) {
    (void)in_sizes; (void)n_in; (void)out_size; (void)ws_size;
    const float* hidden    = (const float*)d_in[0];
    const float* embedding = (const float*)d_in[1];
    const float* w_ih      = (const float*)d_in[2];
    const float* w_hh      = (const float*)d_in[3];
    const float* b_ih      = (const float*)d_in[4];
    const float* b_hh      = (const float*)d_in[5];
    const float* w_out     = (const float*)d_in[6];
    const float* b_out     = (const float*)d_in[7];
    float* out = (float*)d_out;

    float* ws    = (float*)d_ws;
    float* hA    = ws;                        // 4096
    float* hB    = hA + BB * H;               // 4096
    float* psum  = hB + BB * H;               // 2*8*NB
    float* pval  = psum + 2 * 8 * NB;         // 2*8*NB
    int*   pidx  = (int*)(pval + 2 * 8 * NB); // 2*8*NB
    int*   leaf  = pidx + 2 * 8 * NB;         // 64*16 padded counters
    int*   epoch = leaf + 64 * 16;            // 1

    kinit<<<16, 256, 0, stream>>>(hidden, hA, leaf, epoch);
    kmain<<<NB, TPB, 0, stream>>>(embedding, w_ih, w_hh, b_ih, b_hh, w_out, b_out,
                                  hA, hB, psum, pval, pidx, leaf, epoch, out);
}

// Round 8
// 811.310 us; speedup vs baseline: 2.9979x; 2.9979x over previous
//
#include <hip/hip_runtime.h>

#define V 16000
#define E 256
#define H 512
#define HP 516     // padded LDS row stride
#define BB 8       // batch = greedy rows
#define T 12       // lenseq
#define NB 256     // persistent blocks
#define TPB 512    // threads per block
#define AGENT __HIP_MEMORY_SCOPE_AGENT

// Greedy degeneracy verified (R3). Persistent kernel since R4.
// R6 lesson: phase B latency-bound (371 GB/s) + 2.7M LDS bank conflicts.
// R7 lesson: unrolled register prefetch -> spill -> 4.5GB scratch traffic.
//   (but proved ~2 TB/s is reachable at this occupancy)
// R8: TRANSPOSED phase-B mapping: col = lane (tid&63), row = wave (tid>>6).
//   - each wave float4 load of w_out = 64 distinct lines (8KB in flight/instr)
//   - h reads are wave-uniform -> LDS broadcast, zero conflicts
//   - out stores lane-coalesced; row reduction = wave shuffle (no LDS tree)

__device__ __forceinline__ float dot4(float4 a, float4 b) {
    return a.x * b.x + a.y * b.y + a.z * b.z + a.w * b.w;
}

__global__ __launch_bounds__(256) void kinit(const float* __restrict__ hidden,
                                             float* __restrict__ hA,
                                             int* __restrict__ leaf,
                                             int* __restrict__ epoch) {
    int idx = blockIdx.x * 256 + threadIdx.x;
    if (idx < BB * H) hA[idx] = hidden[idx];
    if (idx < 64 * 16) leaf[idx] = 0;
    if (idx == 0) epoch[0] = 0;
}

// stage h rows into padded LDS; coalesced 4B agent loads, conflict-free writes
__device__ __forceinline__ void stage_h(const float* __restrict__ g,
                                        float* __restrict__ s_h, int tid) {
    int r = tid >> 6, lane = tid & 63;
#pragma unroll
    for (int j = 0; j < 8; j++) {
        float x = __hip_atomic_load(g + r * H + lane + 64 * j,
                                    __ATOMIC_RELAXED, AGENT);
        s_h[r * HP + lane + 64 * j] = x;
    }
}

// barrier: leaf arrival (4 blocks/leaf, padded) -> block0 wave0 watches the 64
// leaves -> publishes epoch -> everyone else polls ONE word with ONE lane.
__device__ __forceinline__ void gridbar(int* __restrict__ leaf,
                                        int* __restrict__ epoch, int ep) {
    __syncthreads();
    if (threadIdx.x == 0) {
        int g = blockIdx.x >> 2;
        __hip_atomic_fetch_add(&leaf[g * 16], 1, __ATOMIC_RELEASE, AGENT);
    }
    if (blockIdx.x == 0) {
        if (threadIdx.x < 64) {
            while (__hip_atomic_load(&leaf[threadIdx.x * 16],
                                     __ATOMIC_RELAXED, AGENT) < 4 * ep)
                __builtin_amdgcn_s_sleep(1);
        }
        __syncthreads();
        if (threadIdx.x == 0)
            __hip_atomic_store(epoch, ep, __ATOMIC_RELAXED, AGENT);
    } else {
        if (threadIdx.x == 0) {
            while (__hip_atomic_load(epoch, __ATOMIC_RELAXED, AGENT) < ep)
                __builtin_amdgcn_s_sleep(1);
        }
    }
    __builtin_amdgcn_fence(__ATOMIC_ACQUIRE, "workgroup");
    __syncthreads();
}

__global__ __launch_bounds__(TPB) void kmain(
    const float* __restrict__ emb_tab,
    const float* __restrict__ w_ih,
    const float* __restrict__ w_hh,
    const float* __restrict__ b_ih,
    const float* __restrict__ b_hh,
    const float* __restrict__ w_out,
    const float* __restrict__ b_out,
    float* __restrict__ hA,
    float* __restrict__ hB,
    float* __restrict__ psum,   // [2][8][NB]
    float* __restrict__ pval,
    int* __restrict__ pidx,
    int* __restrict__ leaf,
    int* __restrict__ epoch,
    float* __restrict__ out)
{
    const int blk = blockIdx.x, tid = threadIdx.x;

    __shared__ float s_h[BB * HP];          // 16.5 KB
    __shared__ float s_part[64 * 48];       // 12 KB (phase A only)
    __shared__ float s_S[BB];
    __shared__ int   s_Xn[BB];
    __shared__ int   s_X[BB];

    if (tid < BB) s_X[tid] = 1;             // SOS
    __syncthreads();

    const int lane = tid & 63;
    const int wv   = tid >> 6;              // 0..7 = batch row in phases B/C
    const int v    = blk * 64 + lane;       // vocab col (250 blocks cover V)
    const bool ok  = (v < V);
    float e = 0.f;                          // exp(logit), persists B -> C

    for (int t = 0; t < T; t++) {
        const float* h_cur = (t & 1) ? hB : hA;
        float*       h_nxt = (t & 1) ? hA : hB;
        const int par = t & 1;

        // ---------------- phase A: GRU cell (blocks 0..63) ----------------
        if (blk < 64) {
            stage_h(h_cur, s_h, tid);
            __syncthreads();
            const int jl = tid >> 6;        // 0..7
            const int ar = (tid >> 3) & 7;  // row
            const int kq = tid & 7;         // K split 8
            const int j  = blk * 8 + jl;
            const int pair = jl * 8 + ar;
            float gir = 0.f, giz = 0.f, gin = 0.f, ghr = 0.f, ghz = 0.f, ghn = 0.f;
            {
                const float* erow = emb_tab + (size_t)s_X[ar] * E;
                const float* w0 = w_ih + (size_t)j * E;
                const float* w1 = w0 + (size_t)H * E;
                const float* w2 = w1 + (size_t)H * E;
                const int k0 = kq * (E / 8);
                for (int k = 0; k < E / 8; k += 4) {
                    float4 ev = *(const float4*)(erow + k0 + k);
                    gir += dot4(*(const float4*)(w0 + k0 + k), ev);
                    giz += dot4(*(const float4*)(w1 + k0 + k), ev);
                    gin += dot4(*(const float4*)(w2 + k0 + k), ev);
                }
            }
            {
                const float* hrow = s_h + ar * HP;
                const float* w0 = w_hh + (size_t)j * H;
                const float* w1 = w0 + (size_t)H * H;
                const float* w2 = w1 + (size_t)H * H;
                const int k0 = kq * (H / 8);
                for (int k = 0; k < H / 8; k += 4) {
                    float4 hv = *(const float4*)(hrow + k0 + k);
                    ghr += dot4(*(const float4*)(w0 + k0 + k), hv);
                    ghz += dot4(*(const float4*)(w1 + k0 + k), hv);
                    ghn += dot4(*(const float4*)(w2 + k0 + k), hv);
                }
            }
            float* sp = s_part + pair * 48;
            sp[0 * 8 + kq] = gir; sp[1 * 8 + kq] = giz; sp[2 * 8 + kq] = gin;
            sp[3 * 8 + kq] = ghr; sp[4 * 8 + kq] = ghz; sp[5 * 8 + kq] = ghn;
            __syncthreads();
            if (kq == 0) {
                const float* sp2 = s_part + pair * 48;
                float G[6];
#pragma unroll
                for (int gg = 0; gg < 6; gg++) {
                    float s = 0.f;
#pragma unroll
                    for (int q = 0; q < 8; q++) s += sp2[gg * 8 + q];
                    G[gg] = s;
                }
                float ir  = G[0] + b_ih[j],         hr_ = G[3] + b_hh[j];
                float iz  = G[1] + b_ih[H + j],     hz  = G[4] + b_hh[H + j];
                float inn = G[2] + b_ih[2 * H + j], hn  = G[5] + b_hh[2 * H + j];
                float rg = 1.f / (1.f + __expf(-(ir + hr_)));
                float zg = 1.f / (1.f + __expf(-(iz + hz)));
                float ng = tanhf(inn + rg * hn);
                float ho = s_h[ar * HP + j];
                int xr = s_X[ar];
                bool dn = (xr == 0) || (xr == 2);
                float hv = dn ? ho : ((1.f - zg) * ng + zg * ho);
                __hip_atomic_store(&h_nxt[ar * H + j], hv, __ATOMIC_RELAXED, AGENT);
            }
        }
        gridbar(leaf, epoch, 2 * t + 1);

        // ------- phase B: logits; col=lane (64 lines/wave-load), row=wave ---
        stage_h(h_nxt, s_h, tid);
        __syncthreads();
        {
            const float* w  = w_out + (size_t)(ok ? v : 0) * H;
            const float* hr = s_h + wv * HP;   // wave-uniform -> LDS broadcast
            float a0 = 0.f, a1 = 0.f, a2 = 0.f, a3 = 0.f;
            for (int k = 0; k < H; k += 16) {
                float4 w0 = *(const float4*)(w + k);
                float4 w1 = *(const float4*)(w + k + 4);
                float4 w2 = *(const float4*)(w + k + 8);
                float4 w3 = *(const float4*)(w + k + 12);
                float4 h0 = *(const float4*)(hr + k);
                float4 h1 = *(const float4*)(hr + k + 4);
                float4 h2 = *(const float4*)(hr + k + 8);
                float4 h3 = *(const float4*)(hr + k + 12);
                a0 += dot4(w0, h0); a1 += dot4(w1, h1);
                a2 += dot4(w2, h2); a3 += dot4(w3, h3);
            }
            e = __expf((a0 + a1) + (a2 + a3) + (ok ? b_out[v] : 0.f));

            // wave-level reduce: sum + argmax (tie: value desc, index asc)
            float s  = ok ? e : 0.f;
            float bv = ok ? e : -1.f;
            int   bi = ok ? v : 0x7fffffff;
            for (int m = 1; m < 64; m <<= 1) {
                s += __shfl_xor(s, m, 64);
                float ov = __shfl_xor(bv, m, 64);
                int   oi = __shfl_xor(bi, m, 64);
                if (ov > bv || (ov == bv && oi < bi)) { bv = ov; bi = oi; }
            }
            if (lane == 0) {
                int o = (par * 8 + wv) * NB + blk;   // [par][row][blk]
                __hip_atomic_store(&psum[o], s,  __ATOMIC_RELAXED, AGENT);
                __hip_atomic_store(&pval[o], bv, __ATOMIC_RELAXED, AGENT);
                __hip_atomic_store(&pidx[o], bi, __ATOMIC_RELAXED, AGENT);
            }
        }
        gridbar(leaf, epoch, 2 * t + 2);

        // ------- phase C: redundant global reduce + out write + x update ---
        {
            const int base = (par * 8 + wv) * NB;
            float s = 0.f, bv = -1.f; int bi = 0x7fffffff;
#pragma unroll
            for (int c = 0; c < 4; c++) {       // coalesced: lane-contiguous
                int o = base + lane + 64 * c;
                s += __hip_atomic_load(&psum[o], __ATOMIC_RELAXED, AGENT);
                float ov = __hip_atomic_load(&pval[o], __ATOMIC_RELAXED, AGENT);
                int   oi = __hip_atomic_load(&pidx[o], __ATOMIC_RELAXED, AGENT);
                if (ov > bv || (ov == bv && oi < bi)) { bv = ov; bi = oi; }
            }
            for (int m = 1; m < 64; m <<= 1) {
                s += __shfl_xor(s, m, 64);
                float ov = __shfl_xor(bv, m, 64);
                int   oi = __shfl_xor(bi, m, 64);
                if (ov > bv || (ov == bv && oi < bi)) { bv = ov; bi = oi; }
            }
            if (lane == 0) { s_S[wv] = s; s_Xn[wv] = bi; }
        }
        __syncthreads();
        {
            float* out_t = out + (size_t)t * BB * V;
            int xr = s_X[wv];
            bool dn = (xr == 0) || (xr == 2);
            float inv = 1.f / s_S[wv];
            if (ok) {
                float val = dn ? ((v == 0) ? 1.f : 0.f) : e * inv;
                __builtin_nontemporal_store(val, out_t + wv * V + v);
            }
        }
        __syncthreads();
        if (tid < 8) {
            int xo = s_X[tid];
            s_X[tid] = ((xo == 0) || (xo == 2)) ? 0 : s_Xn[tid];
        }
        __syncthreads();
    }
}

extern "C" void kernel_launch(void* const* d_in, const int* in_sizes, int n_in,
                              void* d_out, int out_size, void* d_ws, size_t ws_size,
                              hipStream_t stream) {
    (void)in_sizes; (void)n_in; (void)out_size; (void)ws_size;
    const float* hidden    = (const float*)d_in[0];
    const float* embedding = (const float*)d_in[1];
    const float* w_ih      = (const float*)d_in[2];
    const float* w_hh      = (const float*)d_in[3];
    const float* b_ih      = (const float*)d_in[4];
    const float* b_hh      = (const float*)d_in[5];
    const float* w_out     = (const float*)d_in[6];
    const float* b_out     = (const float*)d_in[7];
    float* out = (float*)d_out;

    float* ws    = (float*)d_ws;
    float* hA    = ws;                        // 4096
    float* hB    = hA + BB * H;               // 4096
    float* psum  = hB + BB * H;               // 2*8*NB
    float* pval  = psum + 2 * 8 * NB;         // 2*8*NB
    int*   pidx  = (int*)(pval + 2 * 8 * NB); // 2*8*NB
    int*   leaf  = pidx + 2 * 8 * NB;         // 64*16 padded counters
    int*   epoch = leaf + 64 * 16;            // 1

    kinit<<<16, 256, 0, stream>>>(hidden, hA, leaf, epoch);
    kmain<<<NB, TPB, 0, stream>>>(embedding, w_ih, w_hh, b_ih, b_hh, w_out, b_out,
                                  hA, hB, psum, pval, pidx, leaf, epoch, out);
}

// Round 9
// 578.083 us; speedup vs baseline: 4.2074x; 1.4034x over previous
//
#include <hip/hip_runtime.h>

#define V 16000
#define E 256
#define H 512
#define HP 516     // padded LDS h row stride (4-float pad: bank groups 4r)
#define BB 8       // batch rows
#define T 12       // lenseq
#define NB 256     // persistent blocks == CUs (1 block/CU at 159KB LDS)
#define TPB 1024   // 16 waves/block
#define CPB 63     // vocab cols per block (256*63 = 16128 >= 16000)
#define AGENT __HIP_MEMORY_SCOPE_AGENT

// Greedy degeneracy verified (R3). Persistent kernel since R4.
// R6/R8 lesson: phase B is stuck at 300-400 GB/s on a 17 MB/step L2-miss
// stream (per-XCD w_out slice 4.05MB vs 4MB L2 -> structural thrash) and
// load-pattern tweaks don't fix it. R9: w_out lives in LDS. Each block
// stages its 63-col slice (126KB, XOR-swizzled) ONCE; all 12 steps read w
// from LDS. Phase-B global traffic -> 0. Requires dynamic LDS 159KB
// (hipFuncSetAttribute) and 1 block/CU (grid == CU count).

// LDS layout (floats)
constexpr int W_FL   = CPB * 512;            // 32256  swizzled w slice
constexpr int SH_OFF = W_FL;                 // s_h   [8][516]
constexpr int SP_OFF = SH_OFF + BB * HP;     // s_part 64*48 (phase A)
constexpr int RS_OFF = SP_OFF + 64 * 48;     // s_rsum [16][8]
constexpr int RV_OFF = RS_OFF + 128;         // s_rval
constexpr int RI_OFF = RV_OFF + 128;         // s_ridx (int)
constexpr int SS_OFF = RI_OFF + 128;         // s_S   [8]
constexpr int XN_OFF = SS_OFF + 8;           // s_Xn  [8] (int)
constexpr int X_OFF  = XN_OFF + 8;           // s_X   [8] (int)
constexpr int SMEM_FL = X_OFF + 8;
constexpr size_t SMEM_BYTES = (size_t)SMEM_FL * 4;   // 159,488 B < 160 KiB

__device__ __forceinline__ float dot4(float4 a, float4 b) {
    return a.x * b.x + a.y * b.y + a.z * b.z + a.w * b.w;
}

__global__ __launch_bounds__(256) void kinit(const float* __restrict__ hidden,
                                             float* __restrict__ hA,
                                             int* __restrict__ leaf,
                                             int* __restrict__ epoch) {
    int idx = blockIdx.x * 256 + threadIdx.x;
    if (idx < BB * H) hA[idx] = hidden[idx];
    if (idx < 64 * 16) leaf[idx] = 0;
    if (idx == 0) epoch[0] = 0;
}

// barrier: leaf arrival (4 blocks/leaf, padded) -> block0 wave0 watches the 64
// leaves -> publishes epoch -> everyone else polls ONE word with ONE lane.
__device__ __forceinline__ void gridbar(int* __restrict__ leaf,
                                        int* __restrict__ epoch, int ep) {
    __syncthreads();
    if (threadIdx.x == 0) {
        int g = blockIdx.x >> 2;
        __hip_atomic_fetch_add(&leaf[g * 16], 1, __ATOMIC_RELEASE, AGENT);
    }
    if (blockIdx.x == 0) {
        if (threadIdx.x < 64) {
            while (__hip_atomic_load(&leaf[threadIdx.x * 16],
                                     __ATOMIC_RELAXED, AGENT) < 4 * ep)
                __builtin_amdgcn_s_sleep(1);
        }
        __syncthreads();
        if (threadIdx.x == 0)
            __hip_atomic_store(epoch, ep, __ATOMIC_RELAXED, AGENT);
    } else {
        if (threadIdx.x == 0) {
            while (__hip_atomic_load(epoch, __ATOMIC_RELAXED, AGENT) < ep)
                __builtin_amdgcn_s_sleep(1);
        }
    }
    __builtin_amdgcn_fence(__ATOMIC_ACQUIRE, "workgroup");
    __syncthreads();
}

__global__ __launch_bounds__(TPB, 4) void kmain(
    const float* __restrict__ emb_tab,
    const float* __restrict__ w_ih,
    const float* __restrict__ w_hh,
    const float* __restrict__ b_ih,
    const float* __restrict__ b_hh,
    const float* __restrict__ w_out,
    const float* __restrict__ b_out,
    float* __restrict__ hA,
    float* __restrict__ hB,
    float* __restrict__ psum,   // [2][8][NB]
    float* __restrict__ pval,
    int* __restrict__ pidx,
    int* __restrict__ leaf,
    int* __restrict__ epoch,
    float* __restrict__ out)
{
    extern __shared__ float smem[];
    float* w_lds  = smem;
    float* s_h    = smem + SH_OFF;
    float* s_part = smem + SP_OFF;
    float* s_rsum = smem + RS_OFF;
    float* s_rval = smem + RV_OFF;
    int*   s_ridx = (int*)(smem + RI_OFF);
    float* s_S    = smem + SS_OFF;
    int*   s_Xn   = (int*)(smem + XN_OFF);
    int*   s_X    = (int*)(smem + X_OFF);

    const int blk = blockIdx.x, tid = threadIdx.x;

    // ---- stage this block's w_out slice into LDS, swizzled, ONCE ----------
    // layout: w_lds[col*512 + (k ^ ((col&7)<<2))]  (16B blocks preserved)
    for (int i = tid; i < CPB * 128; i += TPB) {
        int col = i >> 7;
        int q4  = (i & 127) << 2;
        int vv  = blk * CPB + col;
        if (vv < V) {
            float4 w4 = *(const float4*)(w_out + (size_t)vv * H + q4);
            *(float4*)(w_lds + col * 512 + (q4 ^ ((col & 7) << 2))) = w4;
        }
    }
    if (tid < BB) s_X[tid] = 1;             // SOS
    __syncthreads();

    // ---- phase-B lane mapping: r=bits0-2, kh=bit3, colw=bits4-5, wave=k? no:
    // col = wave*4 + colw (0..63; 63 = guard), thread dot = (col, r, K-half)
    const int lane = tid & 63;
    const int wv   = tid >> 6;              // 0..15
    const int r    = lane & 7;
    const int kh   = (lane >> 3) & 1;
    const int colw = (lane >> 4) & 3;
    const int col  = wv * 4 + colw;
    const int v    = blk * CPB + col;
    const bool ok  = (col < CPB) && (v < V);
    const int ca   = ok ? col : 0;          // clamped col for LDS reads
    const int swz  = (ca & 7) << 2;
    float e = 0.f;                          // exp(logit), persists B -> C

    for (int t = 0; t < T; t++) {
        const float* h_cur = (t & 1) ? hB : hA;
        float*       h_nxt = (t & 1) ? hA : hB;
        const int par = t & 1;

        // ---------------- phase A: GRU cell (blocks 0..63) ----------------
        if (blk < 64) {                     // stage h_cur into s_h (all 1024)
            int hr = tid >> 7, k4 = (tid & 127) << 2;
            const unsigned long long* p =
                (const unsigned long long*)(h_cur + hr * H + k4);
            union { unsigned long long u; float f[2]; } c0, c1;
            c0.u = __hip_atomic_load(p,     __ATOMIC_RELAXED, AGENT);
            c1.u = __hip_atomic_load(p + 1, __ATOMIC_RELAXED, AGENT);
            s_h[hr * HP + k4]     = c0.f[0]; s_h[hr * HP + k4 + 1] = c0.f[1];
            s_h[hr * HP + k4 + 2] = c1.f[0]; s_h[hr * HP + k4 + 3] = c1.f[1];
        }
        __syncthreads();
        if (blk < 64 && tid < 512) {
            const int jl = tid >> 6;        // 0..7
            const int ar = (tid >> 3) & 7;  // row
            const int kq = tid & 7;         // K split 8
            const int j  = blk * 8 + jl;
            const int pair = jl * 8 + ar;
            float gir = 0.f, giz = 0.f, gin = 0.f, ghr = 0.f, ghz = 0.f, ghn = 0.f;
            {
                const float* erow = emb_tab + (size_t)s_X[ar] * E;
                const float* w0 = w_ih + (size_t)j * E;
                const float* w1 = w0 + (size_t)H * E;
                const float* w2 = w1 + (size_t)H * E;
                const int k0 = kq * (E / 8);
                for (int k = 0; k < E / 8; k += 4) {
                    float4 ev = *(const float4*)(erow + k0 + k);
                    gir += dot4(*(const float4*)(w0 + k0 + k), ev);
                    giz += dot4(*(const float4*)(w1 + k0 + k), ev);
                    gin += dot4(*(const float4*)(w2 + k0 + k), ev);
                }
            }
            {
                const float* hrow = s_h + ar * HP;
                const float* w0 = w_hh + (size_t)j * H;
                const float* w1 = w0 + (size_t)H * H;
                const float* w2 = w1 + (size_t)H * H;
                const int k0 = kq * (H / 8);
                for (int k = 0; k < H / 8; k += 4) {
                    float4 hv = *(const float4*)(hrow + k0 + k);
                    ghr += dot4(*(const float4*)(w0 + k0 + k), hv);
                    ghz += dot4(*(const float4*)(w1 + k0 + k), hv);
                    ghn += dot4(*(const float4*)(w2 + k0 + k), hv);
                }
            }
            float* sp = s_part + pair * 48;
            sp[0 * 8 + kq] = gir; sp[1 * 8 + kq] = giz; sp[2 * 8 + kq] = gin;
            sp[3 * 8 + kq] = ghr; sp[4 * 8 + kq] = ghz; sp[5 * 8 + kq] = ghn;
        }
        __syncthreads();
        if (blk < 64 && tid < 512 && (tid & 7) == 0) {
            const int pair = (tid >> 6) * 8 + ((tid >> 3) & 7);
            const int jl = pair >> 3, ar = pair & 7;
            const int j  = blk * 8 + jl;
            const float* sp2 = s_part + pair * 48;
            float G[6];
#pragma unroll
            for (int gg = 0; gg < 6; gg++) {
                float s = 0.f;
#pragma unroll
                for (int q = 0; q < 8; q++) s += sp2[gg * 8 + q];
                G[gg] = s;
            }
            float ir  = G[0] + b_ih[j],         hr_ = G[3] + b_hh[j];
            float iz  = G[1] + b_ih[H + j],     hz  = G[4] + b_hh[H + j];
            float inn = G[2] + b_ih[2 * H + j], hn  = G[5] + b_hh[2 * H + j];
            float rg = 1.f / (1.f + __expf(-(ir + hr_)));
            float zg = 1.f / (1.f + __expf(-(iz + hz)));
            float ng = tanhf(inn + rg * hn);
            float ho = s_h[ar * HP + j];
            int xr = s_X[ar];
            bool dn = (xr == 0) || (xr == 2);
            float hv = dn ? ho : ((1.f - zg) * ng + zg * ho);
            __hip_atomic_store(&h_nxt[ar * H + j], hv, __ATOMIC_RELAXED, AGENT);
        }
        gridbar(leaf, epoch, 2 * t + 1);

        // -------- phase B: logits from LDS-resident w ----------------------
        {   // stage h_nxt
            int hr = tid >> 7, k4 = (tid & 127) << 2;
            const unsigned long long* p =
                (const unsigned long long*)(h_nxt + hr * H + k4);
            union { unsigned long long u; float f[2]; } c0, c1;
            c0.u = __hip_atomic_load(p,     __ATOMIC_RELAXED, AGENT);
            c1.u = __hip_atomic_load(p + 1, __ATOMIC_RELAXED, AGENT);
            s_h[hr * HP + k4]     = c0.f[0]; s_h[hr * HP + k4 + 1] = c0.f[1];
            s_h[hr * HP + k4 + 2] = c1.f[0]; s_h[hr * HP + k4 + 3] = c1.f[1];
        }
        __syncthreads();
        {
            const float* wb = w_lds + ca * 512;
            const float* hb = s_h + r * HP + kh * 256;
            float acc = 0.f;
            for (int q = 0; q < 256; q += 4) {
                float4 w4 = *(const float4*)(wb + ((kh * 256 + q) ^ swz));
                float4 h4 = *(const float4*)(hb + q);
                acc += dot4(w4, h4);
            }
            // combine K-halves (canonical lo+hi order -> bit-identical on both)
            float other = __shfl_xor(acc, 8, 64);
            float lo = kh ? other : acc;
            float hi = kh ? acc : other;
            e = __expf(lo + hi + (ok ? b_out[v] : 0.f));

            // per-row reduce across this wave's 4 cols (count each col once)
            float s  = (ok && kh == 0) ? e : 0.f;
            float bv = (ok && kh == 0) ? e : -1.f;
            int   bi = (ok && kh == 0) ? v : 0x7fffffff;
#pragma unroll
            for (int m = 8; m <= 32; m <<= 1) {
                s += __shfl_xor(s, m, 64);
                float ov = __shfl_xor(bv, m, 64);
                int   oi = __shfl_xor(bi, m, 64);
                if (ov > bv || (ov == bv && oi < bi)) { bv = ov; bi = oi; }
            }
            if ((lane >> 3) == 0) {         // lanes 0..7 = per-r results
                s_rsum[wv * 8 + r] = s;
                s_rval[wv * 8 + r] = bv;
                s_ridx[wv * 8 + r] = bi;
            }
        }
        __syncthreads();
        if (tid < 64) {                     // reduce 16 waves -> per-row, store
            float s  = s_rsum[tid] + s_rsum[tid + 64];
            float av = s_rval[tid], bv2 = s_rval[tid + 64];
            int   ai = s_ridx[tid], bi2 = s_ridx[tid + 64];
            float bv = av; int bi = ai;
            if (bv2 > bv || (bv2 == bv && bi2 < bi)) { bv = bv2; bi = bi2; }
#pragma unroll
            for (int m = 8; m <= 32; m <<= 1) {
                s += __shfl_xor(s, m, 64);
                float ov = __shfl_xor(bv, m, 64);
                int   oi = __shfl_xor(bi, m, 64);
                if (ov > bv || (ov == bv && oi < bi)) { bv = ov; bi = oi; }
            }
            if (tid < 8) {
                int o = (par * 8 + tid) * NB + blk;
                __hip_atomic_store(&psum[o], s,  __ATOMIC_RELAXED, AGENT);
                __hip_atomic_store(&pval[o], bv, __ATOMIC_RELAXED, AGENT);
                __hip_atomic_store(&pidx[o], bi, __ATOMIC_RELAXED, AGENT);
            }
        }
        gridbar(leaf, epoch, 2 * t + 2);

        // ------- phase C: redundant global reduce + out write + x update ---
        if (wv < 8) {
            const int base = (par * 8 + wv) * NB;
            float s = 0.f, bv = -1.f; int bi = 0x7fffffff;
#pragma unroll
            for (int c = 0; c < 4; c++) {
                int o = base + lane + 64 * c;
                s += __hip_atomic_load(&psum[o], __ATOMIC_RELAXED, AGENT);
                float ov = __hip_atomic_load(&pval[o], __ATOMIC_RELAXED, AGENT);
                int   oi = __hip_atomic_load(&pidx[o], __ATOMIC_RELAXED, AGENT);
                if (ov > bv || (ov == bv && oi < bi)) { bv = ov; bi = oi; }
            }
            for (int m = 1; m < 64; m <<= 1) {
                s += __shfl_xor(s, m, 64);
                float ov = __shfl_xor(bv, m, 64);
                int   oi = __shfl_xor(bi, m, 64);
                if (ov > bv || (ov == bv && oi < bi)) { bv = ov; bi = oi; }
            }
            if (lane == 0) { s_S[wv] = s; s_Xn[wv] = bi; }
        }
        __syncthreads();
        {
            float* out_t = out + (size_t)t * BB * V;
            int xr = s_X[r];
            bool dn = (xr == 0) || (xr == 2);
            float inv = 1.f / s_S[r];
            if (ok && kh == 0) {
                float val = dn ? ((v == 0) ? 1.f : 0.f) : e * inv;
                __builtin_nontemporal_store(val, out_t + r * V + v);
            }
        }
        __syncthreads();
        if (tid < 8) {
            int xo = s_X[tid];
            s_X[tid] = ((xo == 0) || (xo == 2)) ? 0 : s_Xn[tid];
        }
        __syncthreads();
    }
}

extern "C" void kernel_launch(void* const* d_in, const int* in_sizes, int n_in,
                              void* d_out, int out_size, void* d_ws, size_t ws_size,
                              hipStream_t stream) {
    (void)in_sizes; (void)n_in; (void)out_size; (void)ws_size;
    const float* hidden    = (const float*)d_in[0];
    const float* embedding = (const float*)d_in[1];
    const float* w_ih      = (const float*)d_in[2];
    const float* w_hh      = (const float*)d_in[3];
    const float* b_ih      = (const float*)d_in[4];
    const float* b_hh      = (const float*)d_in[5];
    const float* w_out     = (const float*)d_in[6];
    const float* b_out     = (const float*)d_in[7];
    float* out = (float*)d_out;

    float* ws    = (float*)d_ws;
    float* hA    = ws;                        // 4096
    float* hB    = hA + BB * H;               // 4096
    float* psum  = hB + BB * H;               // 2*8*NB
    float* pval  = psum + 2 * 8 * NB;         // 2*8*NB
    int*   pidx  = (int*)(pval + 2 * 8 * NB); // 2*8*NB
    int*   leaf  = pidx + 2 * 8 * NB;         // 64*16 padded counters
    int*   epoch = leaf + 64 * 16;            // 1

    static bool attr_set = false;             // idempotent attribute, not a
    hipFuncSetAttribute((const void*)kmain,   // stream op (capture-safe);
        hipFuncAttributeMaxDynamicSharedMemorySize,  // call every time is fine
        (int)SMEM_BYTES);
    (void)attr_set;

    kinit<<<16, 256, 0, stream>>>(hidden, hA, leaf, epoch);
    kmain<<<NB, TPB, SMEM_BYTES, stream>>>(embedding, w_ih, w_hh, b_ih, b_hh,
                                           w_out, b_out, hA, hB, psum, pval,
                                           pidx, leaf, epoch, out);
}